// Round 17
// baseline (106.584 us; speedup 1.0000x reference)
//
#include <hip/hip_runtime.h>

#define NRAYS 8192
#define NS    256
#define HID   64
#define RPB   4      // rays per block, one wave per ray
#define EP    260    // sE row stride in floats

typedef _Float16 f16x2 __attribute__((ext_vector_type(2)));
typedef _Float16 f16x8 __attribute__((ext_vector_type(8)));
typedef float    f32x4 __attribute__((ext_vector_type(4)));

#define WAVE_LDS_FENCE() asm volatile("s_waitcnt lgkmcnt(0)" ::: "memory")

// ---------------- kernel 1 (split path): precompute per-ray constants ----
// AB layout per ray (256 B): [A0..A63][B0..B63] as f16.
// dw layout per ray: 4 floats {dwr,dwg,dwb,pad}.
// WB: Wout fragments, lo[128] f16 then hi[128] f16: index (q*4+n)*8+j.
__global__ __launch_bounds__(256) void prep_kernel(
    const float* __restrict__ ray_start,
    const float* __restrict__ ray_dir,
    const float* __restrict__ W1,
    const float* __restrict__ b1,
    const float* __restrict__ w_sigma,
    const float* __restrict__ W_rgb,
    const float* __restrict__ W_dir,
    const float* __restrict__ b_rgb,
    _Float16* __restrict__ AB,
    float* __restrict__ dw,
    _Float16* __restrict__ WB)
{
    const int t   = threadIdx.x;
    const int ray = blockIdx.x * 4 + (t >> 6);
    const int h   = t & 63;

    const float ox = ray_start[ray*3+0], oy = ray_start[ray*3+1], oz = ray_start[ray*3+2];
    const float dx = ray_dir[ray*3+0],  dy = ray_dir[ray*3+1],  dz = ray_dir[ray*3+2];
    const float w0 = W1[h], w1 = W1[HID + h], w2 = W1[2*HID + h];
    const float A = fmaf(w0, ox, fmaf(w1, oy, fmaf(w2, oz, b1[h])));
    const float B = fmaf(w0, dx, fmaf(w1, dy, w2 * dz));
    AB[ray*128 + h]      = (_Float16)A;
    AB[ray*128 + 64 + h] = (_Float16)B;

    if (h < 3)
        dw[ray*4 + h] = fmaf(dx, W_dir[0*3+h], fmaf(dy, W_dir[1*3+h],
                         fmaf(dz, W_dir[2*3+h], b_rgb[h])));

    if (blockIdx.x == 0 && t < 128) {
        const int j = t & 7, n = (t >> 3) & 3, q = t >> 5;
        const int klo = q*8 + j, khi = 32 + q*8 + j;
        const float vlo = (n == 0) ? w_sigma[klo] : W_rgb[klo*3 + (n-1)];
        const float vhi = (n == 0) ? w_sigma[khi] : W_rgb[khi*3 + (n-1)];
        WB[(q*4 + n)*8 + j]       = (_Float16)vlo;
        WB[128 + (q*4 + n)*8 + j] = (_Float16)vhi;
    }
}

// ---------------- kernel 2 (split path): render from warm constants ----
__global__ __launch_bounds__(256) void vr_split(
    const float* __restrict__ sampled_depth,
    const float* __restrict__ sampled_dists,
    const int*   __restrict__ sampled_idx,
    const _Float16* __restrict__ AB,
    const float* __restrict__ dw,
    const _Float16* __restrict__ WB,
    float* __restrict__ out)
{
    __shared__ _Float16 sDep[RPB][NS];
    __shared__ float    sE[RPB][4][EP];

    const int t    = threadIdx.x;
    const int lane = t & 63;
    const int wv   = t >> 6;
    const int ray  = blockIdx.x * RPB + wv;
    const int n    = lane & 15;
    const int q    = lane >> 4;

    const _Float16* abr = AB + (size_t)ray * 128;
    const f16x8 Alo = *(const f16x8*)(abr + q*8);
    const f16x8 Ahi = *(const f16x8*)(abr + 32 + q*8);
    const f16x8 Blo = *(const f16x8*)(abr + 64 + q*8);
    const f16x8 Bhi = *(const f16x8*)(abr + 96 + q*8);

    f16x8 bflo = (f16x8)(_Float16)0.f;
    f16x8 bfhi = (f16x8)(_Float16)0.f;
    if (n < 4) {
        bflo = *(const f16x8*)(WB + (q*4 + n)*8);
        bfhi = *(const f16x8*)(WB + 128 + (q*4 + n)*8);
    }

    const float dwr = dw[ray*4 + 0];
    const float dwg = dw[ray*4 + 1];
    const float dwb = dw[ray*4 + 2];

    const size_t rbase = (size_t)ray * NS + (size_t)lane * 4;
    const float4 dep = *(const float4*)(sampled_depth + rbase);
    const float4 dst = *(const float4*)(sampled_dists + rbase);
    const int4  vidx = *(const int4*)(sampled_idx + rbase);

    {
        f16x2 dl; dl.x = (_Float16)dep.x; dl.y = (_Float16)dep.y;
        f16x2 dh; dh.x = (_Float16)dep.z; dh.y = (_Float16)dep.w;
        f16x2* dp = (f16x2*)&sDep[wv][4*lane];
        dp[0] = dl; dp[1] = dh;
    }
    WAVE_LDS_FENCE();

    const f16x8 z8 = (f16x8)(_Float16)0.f;

#pragma unroll
    for (int tt = 0; tt < 16; ++tt) {
        const _Float16 dv = sDep[wv][16*tt + n];
        f16x8 d8;
#pragma unroll
        for (int j = 0; j < 8; ++j) d8[j] = dv;
        f16x8 hlo = __builtin_elementwise_fma(Blo, d8, Alo);
        f16x8 hhi = __builtin_elementwise_fma(Bhi, d8, Ahi);
        hlo = __builtin_elementwise_max(hlo, z8);
        hhi = __builtin_elementwise_max(hhi, z8);
        f32x4 acc = {0.f, 0.f, 0.f, 0.f};
        acc = __builtin_amdgcn_mfma_f32_16x16x32_f16(hlo, bflo, acc, 0, 0, 0);
        acc = __builtin_amdgcn_mfma_f32_16x16x32_f16(hhi, bfhi, acc, 0, 0, 0);
        if (n < 4)
            *(f32x4*)&sE[wv][n][16*tt + 4*q] = acc;
    }
    WAVE_LDS_FENCE();

    const f32x4 sg4 = *(const f32x4*)&sE[wv][0][4*lane];
    const f32x4 cr4 = *(const f32x4*)&sE[wv][1][4*lane];
    const f32x4 cg4 = *(const f32x4*)&sE[wv][2][4*lane];
    const f32x4 cb4 = *(const f32x4*)&sE[wv][3][4*lane];

    const float dpt[4] = {dep.x, dep.y, dep.z, dep.w};
    const float dsv[4] = {dst.x, dst.y, dst.z, dst.w};
    const int   vid[4] = {vidx.x, vidx.y, vidx.z, vidx.w};

    float c[4];
    float run = 0.f;
#pragma unroll
    for (int j = 0; j < 4; ++j) {
        float f = fmaxf(sg4[j], 0.f) * dsv[j] * 7.0f;
        if (vid[j] == -1) f = 0.f;
        run += f;
        c[j] = run;
    }

    float tot = run;
#pragma unroll
    for (int off = 1; off < 64; off <<= 1) {
        const float v = __shfl_up(tot, off, 64);
        if (lane >= off) tot += v;
    }
    const float base = tot - run;

    float Eprev = __expf(-base);
    float prob[4];
    float s0 = 0.f, s1 = 0.f, s2 = 0.f, s3 = 0.f, s4 = 0.f;
#pragma unroll
    for (int j = 0; j < 4; ++j) {
        const float Ej = __expf(-(base + c[j]));
        const float p  = Eprev - Ej;
        Eprev = Ej;
        prob[j] = p;
        const float rr = __builtin_amdgcn_rcpf(1.f + __expf(-(cr4[j] + dwr)));
        const float gg = __builtin_amdgcn_rcpf(1.f + __expf(-(cg4[j] + dwg)));
        const float bb = __builtin_amdgcn_rcpf(1.f + __expf(-(cb4[j] + dwb)));
        s0 += p;
        s1 = fmaf(dpt[j], p, s1);
        s2 = fmaf(rr, p, s2);
        s3 = fmaf(gg, p, s3);
        s4 = fmaf(bb, p, s4);
    }

    float* orow = out + (size_t)ray * (NS + 5);
#pragma unroll
    for (int j = 0; j < 4; ++j)
        orow[5 + 4*lane + j] = prob[j];

#pragma unroll
    for (int off = 32; off >= 1; off >>= 1) {
        s0 += __shfl_xor(s0, off, 64);
        s1 += __shfl_xor(s1, off, 64);
        s2 += __shfl_xor(s2, off, 64);
        s3 += __shfl_xor(s3, off, 64);
        s4 += __shfl_xor(s4, off, 64);
    }

    if (lane == 0) {
        orow[0] = s2;
        orow[1] = s3;
        orow[2] = s4;
        orow[3] = s1;
        orow[4] = 1.f - s0;
    }
}

// ---------------- fallback: R14 fused kernel (no workspace) ----------------
__global__ __launch_bounds__(256) void vr_fused(
    const float* __restrict__ ray_start,
    const float* __restrict__ ray_dir,
    const float* __restrict__ sampled_depth,
    const float* __restrict__ sampled_dists,
    const int*   __restrict__ sampled_idx,
    const float* __restrict__ W1,
    const float* __restrict__ b1,
    const float* __restrict__ w_sigma,
    const float* __restrict__ W_rgb,
    const float* __restrict__ W_dir,
    const float* __restrict__ b_rgb,
    float* __restrict__ out)
{
    __shared__ _Float16 sA[RPB][HID];
    __shared__ _Float16 sB[RPB][HID];
    __shared__ _Float16 sDep[RPB][NS];
    __shared__ float    sE[RPB][4][EP];

    const int t    = threadIdx.x;
    const int lane = t & 63;
    const int wv   = t >> 6;
    const int ray  = blockIdx.x * RPB + wv;

    const float ox = ray_start[ray*3+0], oy = ray_start[ray*3+1], oz = ray_start[ray*3+2];
    const float dx = ray_dir[ray*3+0],  dy = ray_dir[ray*3+1],  dz = ray_dir[ray*3+2];
    {
        const int h = lane;
        const float w0 = W1[h], w1 = W1[HID + h], w2 = W1[2*HID + h];
        const float A = fmaf(w0, ox, fmaf(w1, oy, fmaf(w2, oz, b1[h])));
        const float B = fmaf(w0, dx, fmaf(w1, dy, w2 * dz));
        sA[wv][h] = (_Float16)A;
        sB[wv][h] = (_Float16)B;
    }

    const float dwr = fmaf(dx, W_dir[0], fmaf(dy, W_dir[3], fmaf(dz, W_dir[6], b_rgb[0])));
    const float dwg = fmaf(dx, W_dir[1], fmaf(dy, W_dir[4], fmaf(dz, W_dir[7], b_rgb[1])));
    const float dwb = fmaf(dx, W_dir[2], fmaf(dy, W_dir[5], fmaf(dz, W_dir[8], b_rgb[2])));

    const size_t rbase = (size_t)ray * NS + (size_t)lane * 4;
    const float4 dep = *(const float4*)(sampled_depth + rbase);
    const float4 dst = *(const float4*)(sampled_dists + rbase);
    const int4  vidx = *(const int4*)(sampled_idx + rbase);

    {
        f16x2 dl; dl.x = (_Float16)dep.x; dl.y = (_Float16)dep.y;
        f16x2 dh; dh.x = (_Float16)dep.z; dh.y = (_Float16)dep.w;
        f16x2* dp = (f16x2*)&sDep[wv][4*lane];
        dp[0] = dl; dp[1] = dh;
    }

    const int n = lane & 15;
    const int q = lane >> 4;
    f16x8 bflo = (f16x8)(_Float16)0.f;
    f16x8 bfhi = (f16x8)(_Float16)0.f;
    if (n < 4) {
#pragma unroll
        for (int j = 0; j < 8; ++j) {
            const int klo = q*8 + j, khi = 32 + q*8 + j;
            const float vlo = (n == 0) ? w_sigma[klo] : W_rgb[klo*3 + (n-1)];
            const float vhi = (n == 0) ? w_sigma[khi] : W_rgb[khi*3 + (n-1)];
            bflo[j] = (_Float16)vlo;
            bfhi[j] = (_Float16)vhi;
        }
    }

    WAVE_LDS_FENCE();

    const f16x8 Alo = *(const f16x8*)&sA[wv][q*8];
    const f16x8 Ahi = *(const f16x8*)&sA[wv][32 + q*8];
    const f16x8 Blo = *(const f16x8*)&sB[wv][q*8];
    const f16x8 Bhi = *(const f16x8*)&sB[wv][32 + q*8];
    const f16x8 z8  = (f16x8)(_Float16)0.f;

#pragma unroll
    for (int tt = 0; tt < 16; ++tt) {
        const _Float16 dv = sDep[wv][16*tt + n];
        f16x8 d8;
#pragma unroll
        for (int j = 0; j < 8; ++j) d8[j] = dv;
        f16x8 hlo = __builtin_elementwise_fma(Blo, d8, Alo);
        f16x8 hhi = __builtin_elementwise_fma(Bhi, d8, Ahi);
        hlo = __builtin_elementwise_max(hlo, z8);
        hhi = __builtin_elementwise_max(hhi, z8);
        f32x4 acc = {0.f, 0.f, 0.f, 0.f};
        acc = __builtin_amdgcn_mfma_f32_16x16x32_f16(hlo, bflo, acc, 0, 0, 0);
        acc = __builtin_amdgcn_mfma_f32_16x16x32_f16(hhi, bfhi, acc, 0, 0, 0);
        if (n < 4)
            *(f32x4*)&sE[wv][n][16*tt + 4*q] = acc;
    }

    WAVE_LDS_FENCE();

    const f32x4 sg4 = *(const f32x4*)&sE[wv][0][4*lane];
    const f32x4 cr4 = *(const f32x4*)&sE[wv][1][4*lane];
    const f32x4 cg4 = *(const f32x4*)&sE[wv][2][4*lane];
    const f32x4 cb4 = *(const f32x4*)&sE[wv][3][4*lane];

    const float dpt[4] = {dep.x, dep.y, dep.z, dep.w};
    const float dsv[4] = {dst.x, dst.y, dst.z, dst.w};
    const int   vid[4] = {vidx.x, vidx.y, vidx.z, vidx.w};

    float c[4];
    float run = 0.f;
#pragma unroll
    for (int j = 0; j < 4; ++j) {
        float f = fmaxf(sg4[j], 0.f) * dsv[j] * 7.0f;
        if (vid[j] == -1) f = 0.f;
        run += f;
        c[j] = run;
    }

    float tot = run;
#pragma unroll
    for (int off = 1; off < 64; off <<= 1) {
        const float v = __shfl_up(tot, off, 64);
        if (lane >= off) tot += v;
    }
    const float base = tot - run;

    float Eprev = __expf(-base);
    float prob[4];
    float s0 = 0.f, s1 = 0.f, s2 = 0.f, s3 = 0.f, s4 = 0.f;
#pragma unroll
    for (int j = 0; j < 4; ++j) {
        const float Ej = __expf(-(base + c[j]));
        const float p  = Eprev - Ej;
        Eprev = Ej;
        prob[j] = p;
        const float rr = __builtin_amdgcn_rcpf(1.f + __expf(-(cr4[j] + dwr)));
        const float gg = __builtin_amdgcn_rcpf(1.f + __expf(-(cg4[j] + dwg)));
        const float bb = __builtin_amdgcn_rcpf(1.f + __expf(-(cb4[j] + dwb)));
        s0 += p;
        s1 = fmaf(dpt[j], p, s1);
        s2 = fmaf(rr, p, s2);
        s3 = fmaf(gg, p, s3);
        s4 = fmaf(bb, p, s4);
    }

    float* orow = out + (size_t)ray * (NS + 5);
#pragma unroll
    for (int j = 0; j < 4; ++j)
        orow[5 + 4*lane + j] = prob[j];

#pragma unroll
    for (int off = 32; off >= 1; off >>= 1) {
        s0 += __shfl_xor(s0, off, 64);
        s1 += __shfl_xor(s1, off, 64);
        s2 += __shfl_xor(s2, off, 64);
        s3 += __shfl_xor(s3, off, 64);
        s4 += __shfl_xor(s4, off, 64);
    }

    if (lane == 0) {
        orow[0] = s2;
        orow[1] = s3;
        orow[2] = s4;
        orow[3] = s1;
        orow[4] = 1.f - s0;
    }
}

extern "C" void kernel_launch(void* const* d_in, const int* in_sizes, int n_in,
                              void* d_out, int out_size, void* d_ws, size_t ws_size,
                              hipStream_t stream)
{
    // workspace layout: AB (2 MB) | dw (128 KB) | WB (512 B)
    const size_t NEED = 2u*1024u*1024u + 128u*1024u + 512u;

    if (d_ws != nullptr && ws_size >= NEED) {
        char* ws = (char*)d_ws;
        _Float16* AB  = (_Float16*)ws;
        float*    dwv = (float*)(ws + 2u*1024u*1024u);
        _Float16* WB  = (_Float16*)(ws + 2u*1024u*1024u + 128u*1024u);

        prep_kernel<<<NRAYS / 4, 256, 0, stream>>>(
            (const float*)d_in[0], (const float*)d_in[1],
            (const float*)d_in[5], (const float*)d_in[6],
            (const float*)d_in[7], (const float*)d_in[8],
            (const float*)d_in[9], (const float*)d_in[10],
            AB, dwv, WB);

        vr_split<<<NRAYS / RPB, 256, 0, stream>>>(
            (const float*)d_in[2], (const float*)d_in[3], (const int*)d_in[4],
            AB, dwv, WB, (float*)d_out);
    } else {
        vr_fused<<<NRAYS / RPB, 256, 0, stream>>>(
            (const float*)d_in[0], (const float*)d_in[1],
            (const float*)d_in[2], (const float*)d_in[3], (const int*)d_in[4],
            (const float*)d_in[5], (const float*)d_in[6],
            (const float*)d_in[7], (const float*)d_in[8],
            (const float*)d_in[9], (const float*)d_in[10],
            (float*)d_out);
    }
}